// Round 4
// baseline (330.263 us; speedup 1.0000x reference)
//
#include <hip/hip_runtime.h>
#include <hip/hip_cooperative_groups.h>

namespace coop = cooperative_groups;

typedef _Float16 f16x8 __attribute__((ext_vector_type(8)));
typedef float    f32x4 __attribute__((ext_vector_type(4)));

namespace {
constexpr int Bb = 8, Cc = 256, Oo = 256;
constexpr int HW = 4096;                 // 64x64
constexpr int NCHUNK = 72;               // 2304 / 32
constexpr int SROW = 40;                 // Sl row stride (f16), pad 32->40
}

__device__ inline f16x8 sp8(_Float16 x) { f16x8 r = {x,x,x,x,x,x,x,x}; return r; }

// Single cooperative kernel: phase0 (NCHW->NHWC fp16 + weight cvt) -> grid.sync -> phase1 (MFMA implicit GEMM)
// grid = 256 blocks (b = bid&7 -> XCD affinity), 1024 threads (16 waves/CU).
__global__ __launch_bounds__(1024, 4)
void dcn_fused(const float* __restrict__ inp,
               const float* __restrict__ offset,
               const float* __restrict__ mask,
               const float* __restrict__ weight,
               const float* __restrict__ bias,
               float* __restrict__ out,
               _Float16* __restrict__ inh,    // [B][4096][256] fp16 NHWC (ws)
               _Float16* __restrict__ wgh) {  // [72][4][256][8] fp16 (ws)
  __shared__ __align__(16) _Float16 Wl[2][8192];        // 32 KB
  __shared__ __align__(16) _Float16 Sl[2][128 * SROW];  // 20 KB

  const int tid = threadIdx.x;
  const int bid = blockIdx.x;
  const int b   = bid & 7;     // batch -> XCD (linear id % 8)
  const int rp  = bid >> 3;    // 0..31 : rows 2rp, 2rp+1

  // ================= phase 0a: transpose own slab (128 px x 256 c) =================
  {
    const int px   = tid >> 3;     // 0..127
    const int slot = tid & 7;      // 0..7
    const float* src = inp + (size_t)b * Cc * HW + rp * 128 + px;
    _Float16*    dst = inh + ((size_t)b * HW + rp * 128 + px) * Cc;
#pragma unroll
    for (int q = 0; q < 4; ++q) {
      int c8 = q * 8 + slot;
      f16x8 v;
#pragma unroll
      for (int j = 0; j < 8; ++j)
        v[j] = (_Float16)src[(size_t)(c8 * 8 + j) * HW];
      *(f16x8*)(dst + c8 * 8) = v;
    }
  }
  // ================= phase 0b: weight fp32 [O][C][9] -> fp16 [chunk][kq][o][k8] ====
  if (tid < 288) {
    int t   = bid * 288 + tid;     // 0..73727
    int o   = t & 255;
    int Kb  = (t >> 8) * 8;
    const float* s = weight + (size_t)o * 2304;
    f16x8 v;
#pragma unroll
    for (int k8 = 0; k8 < 8; ++k8) {
      int K = Kb + k8;
      int tap = K >> 8, c = K & 255;
      v[k8] = (_Float16)s[c * 9 + tap];
    }
    *(f16x8*)(wgh + (size_t)t * 8) = v;
  }

  __threadfence();
  coop::this_grid().sync();

  // ================= phase 1: 256(o) x 128(p) implicit GEMM =================
  const bool samp = tid < 512;
  const int pos = (tid >> 2) & 127;   // sampling: position
  const int cgc = tid & 3;            // sampling: channel octet (4 lanes x 16B = 64B/pixel)
  const int ho  = rp * 2 + (pos >> 6), wo = pos & 63;
  const int u   = tid & 511;          // weight-stager slot
  const int lane = tid & 63, wid = tid >> 6;
  const int wm = wid >> 2, wn = wid & 3;   // wave tile 64(o) x 32(p)
  const int lq = lane >> 4, lr = lane & 15;

  const f16x8* gin = (const f16x8*)(inh + (size_t)b * HW * Cc);
  const uint4* wg4 = (const uint4*)wgh;

  int4   mi;   float4 mwt;
  f16x8  v0, v1, v2, v3;
  uint4  wv0, wv1;

  auto compute_md = [&](int tap) {
    float offy = offset[(((size_t)b * 18 + 2 * tap)     * 64 + ho) * 64 + wo];
    float offx = offset[(((size_t)b * 18 + 2 * tap + 1) * 64 + ho) * 64 + wo];
    float m    = mask  [(((size_t)b * 9  + tap)         * 64 + ho) * 64 + wo];
    int ki = tap / 3, kj = tap % 3;
    float y = offy + (float)(ho - 1 + ki);
    float x = offx + (float)(wo - 1 + kj);
    float y0f = floorf(y), x0f = floorf(x);
    float ly = y - y0f, lx = x - x0f;
    float hy = 1.f - ly, hx = 1.f - lx;
    int y0 = (int)y0f, x0 = (int)x0f;
    int y1 = y0 + 1, x1 = x0 + 1;
    bool vy0 = (unsigned)y0 < 64u, vy1 = (unsigned)y1 < 64u;
    bool vx0 = (unsigned)x0 < 64u, vx1 = (unsigned)x1 < 64u;
    int cy0 = min(max(y0, 0), 63), cy1 = min(max(y1, 0), 63);
    int cx0 = min(max(x0, 0), 63), cx1 = min(max(x1, 0), 63);
    mwt.x = (vy0 && vx0) ? hy * hx * m : 0.f;
    mwt.y = (vy0 && vx1) ? hy * lx * m : 0.f;
    mwt.z = (vy1 && vx0) ? ly * hx * m : 0.f;
    mwt.w = (vy1 && vx1) ? ly * lx * m : 0.f;
    mi = make_int4(cy0 * 64 + cx0, cy0 * 64 + cx1, cy1 * 64 + cx0, cy1 * 64 + cx1);
  };

  auto fetch = [&](int c) {
    if (samp) {
      if ((c & 7) == 0) compute_md(c >> 3);
      int cb = (c & 7) * 4 + cgc;
      v0 = gin[mi.x * 32 + cb];
      v1 = gin[mi.y * 32 + cb];
      v2 = gin[mi.z * 32 + cb];
      v3 = gin[mi.w * 32 + cb];
    } else {
      wv0 = wg4[c * 1024 + u];
      wv1 = wg4[c * 1024 + 512 + u];
    }
  };

  auto stage = [&](int nb) {
    if (samp) {
      f16x8 s = v0 * sp8((_Float16)mwt.x) + v1 * sp8((_Float16)mwt.y)
              + v2 * sp8((_Float16)mwt.z) + v3 * sp8((_Float16)mwt.w);
      *(f16x8*)(&Sl[nb][pos * SROW + cgc * 8]) = s;
    } else {
      ((uint4*)&Wl[nb][0])[u]       = wv0;
      ((uint4*)&Wl[nb][0])[512 + u] = wv1;
    }
  };

  f32x4 acc[4][2];
#pragma unroll
  for (int mt = 0; mt < 4; ++mt)
#pragma unroll
    for (int nt = 0; nt < 2; ++nt) {
      acc[mt][nt][0] = 0.f; acc[mt][nt][1] = 0.f;
      acc[mt][nt][2] = 0.f; acc[mt][nt][3] = 0.f;
    }

  // prologue
  fetch(0);
  stage(0);
  __syncthreads();

  for (int c = 0; c < NCHUNK; ++c) {
    const int cur = c & 1;
    if (c + 1 < NCHUNK) fetch(c + 1);   // loads in flight during MFMA

    const _Float16* WlB = &Wl[cur][lq * 2048 + (wm * 64 + lr) * 8];
    const _Float16* SlB = &Sl[cur][(wn * 32 + lr) * SROW + lq * 8];
    f16x8 afr[4];
#pragma unroll
    for (int mt = 0; mt < 4; ++mt) afr[mt] = *(const f16x8*)(WlB + mt * 128);
#pragma unroll
    for (int nt = 0; nt < 2; ++nt) {
      f16x8 bfr = *(const f16x8*)(SlB + nt * 16 * SROW);
#pragma unroll
      for (int mt = 0; mt < 4; ++mt)
        acc[mt][nt] = __builtin_amdgcn_mfma_f32_16x16x32_f16(afr[mt], bfr, acc[mt][nt], 0, 0, 0);
    }
    if (c + 1 < NCHUNK) stage(cur ^ 1);
    __syncthreads();
  }

  // ---- epilogue: bias + store ----
  const int pbase = rp * 128 + wn * 32 + lr;
#pragma unroll
  for (int mt = 0; mt < 4; ++mt) {
#pragma unroll
    for (int reg = 0; reg < 4; ++reg) {
      int o = wm * 64 + mt * 16 + lq * 4 + reg;
      float bv = bias[o];
      float* op = out + ((size_t)(b * 256 + o)) * 4096 + pbase;
      op[0]  = acc[mt][0][reg] + bv;
      op[16] = acc[mt][1][reg] + bv;
    }
  }
}

extern "C" void kernel_launch(void* const* d_in, const int* in_sizes, int n_in,
                              void* d_out, int out_size, void* d_ws, size_t ws_size,
                              hipStream_t stream) {
  const float* inp    = (const float*)d_in[0];
  const float* offset = (const float*)d_in[1];
  const float* mask   = (const float*)d_in[2];
  const float* weight = (const float*)d_in[3];
  const float* bias   = (const float*)d_in[4];
  float* out = (float*)d_out;

  _Float16* inh = (_Float16*)d_ws;                       // 16.78 MB
  _Float16* wgh = inh + (size_t)Bb * HW * Cc;            // +1.18 MB

  void* args[] = { (void*)&inp, (void*)&offset, (void*)&mask, (void*)&weight,
                   (void*)&bias, (void*)&out, (void*)&inh, (void*)&wgh };
  hipLaunchCooperativeKernel((const void*)dcn_fused, dim3(256), dim3(1024),
                             args, 0, stream);
}

// Round 5
// 285.564 us; speedup vs baseline: 1.1565x; 1.1565x over previous
//
#include <hip/hip_runtime.h>

typedef _Float16 f16x8 __attribute__((ext_vector_type(8)));
typedef float    f32x4 __attribute__((ext_vector_type(4)));

namespace {
constexpr int Bb = 8, Cc = 256, Oo = 256;
constexpr int HW = 4096;                 // 64x64
constexpr int NCHUNK = 72;               // 2304 / 32
constexpr int SROW = 40;                 // Sl row stride (f16), pad 32->40
}

__device__ inline f16x8 sp8(_Float16 x) { f16x8 r = {x,x,x,x,x,x,x,x}; return r; }

// ---------- pre-kernel 1: NCHW fp32 -> NHWC fp16 (R3 verbatim) ----------
__global__ __launch_bounds__(256)
void nchw_to_nhwc_f16(const float* __restrict__ in, _Float16* __restrict__ outh) {
  const int tid = threadIdx.x;
  const int b   = blockIdx.y;
  const int px  = blockIdx.x * 32 + (tid >> 3);
  const int c8s = tid & 7;
  const float* src = in + (size_t)b * Cc * HW + px;
  _Float16*    dst = outh + ((size_t)b * HW + px) * Cc;
#pragma unroll
  for (int q = 0; q < 4; ++q) {
    int c8 = q * 8 + c8s;
    f16x8 v;
#pragma unroll
    for (int j = 0; j < 8; ++j)
      v[j] = (_Float16)src[(size_t)(c8 * 8 + j) * HW];
    *(f16x8*)(dst + c8 * 8) = v;
  }
}

// ---------- pre-kernel 2: weight fp32 [O][C][9] -> fp16 [chunk][kq][o][k8] ----------
__global__ __launch_bounds__(256)
void wcvt(const float* __restrict__ w, _Float16* __restrict__ wh) {
  int t   = blockIdx.x * 256 + threadIdx.x;   // 0..73727
  int o   = t & 255;
  int Kb  = (t >> 8) * 8;
  const float* s = w + (size_t)o * 2304;
  f16x8 v;
#pragma unroll
  for (int k8 = 0; k8 < 8; ++k8) {
    int K = Kb + k8;
    int tap = K >> 8, c = K & 255;
    v[k8] = (_Float16)s[c * 9 + tap];
  }
  *(f16x8*)(wh + (size_t)t * 8) = v;
}

// ---------- main kernel: 256(o) x 64(p) tile, 256 threads, 2 blocks/CU ----------
// grid (x=b, y=row): linear id % 8 == b -> XCD-affine batches (L2-resident image)
__global__ __launch_bounds__(256, 2)
void dcn_mfma(const _Float16* __restrict__ inh,   // [B][4096][256] fp16 NHWC
              const _Float16* __restrict__ wgh,   // [72][4][256][8] fp16
              const float* __restrict__ offset,
              const float* __restrict__ mask,
              const float* __restrict__ bias,
              float* __restrict__ out) {
  __shared__ __align__(16) _Float16 Wl[2][8192];       // 32 KB
  __shared__ __align__(16) _Float16 Sl[2][64 * SROW];  // 10 KB

  const int tid = threadIdx.x;
  const int b   = blockIdx.x;   // 0..7  -> XCD
  const int rp  = blockIdx.y;   // 0..63 -> one output row

  // sampling role: pos = wo in [0,64), cg in [0,4) (8 ch each; 4 lanes = 64 B/pixel)
  const int pos = tid >> 2, cg = tid & 3;
  const int ho  = rp, wo = pos;
  // MFMA role: 4 waves, wave tile 64(o) x 64(p)
  const int lane = tid & 63, wm = tid >> 6;
  const int lq = lane >> 4, lr = lane & 15;

  const f16x8* gin = (const f16x8*)(inh + (size_t)b * HW * Cc);
  const uint4* wg4 = (const uint4*)wgh;

  int4   mi;   float4 mwt;
  f16x8  v0, v1, v2, v3;
  uint4  wv[4];

  auto compute_md = [&](int tap) {
    float offy = offset[(((size_t)b * 18 + 2 * tap)     * 64 + ho) * 64 + wo];
    float offx = offset[(((size_t)b * 18 + 2 * tap + 1) * 64 + ho) * 64 + wo];
    float m    = mask  [(((size_t)b * 9  + tap)         * 64 + ho) * 64 + wo];
    int ki = tap / 3, kj = tap % 3;
    float y = offy + (float)(ho - 1 + ki);
    float x = offx + (float)(wo - 1 + kj);
    float y0f = floorf(y), x0f = floorf(x);
    float ly = y - y0f, lx = x - x0f;
    float hy = 1.f - ly, hx = 1.f - lx;
    int y0 = (int)y0f, x0 = (int)x0f;
    int y1 = y0 + 1, x1 = x0 + 1;
    bool vy0 = (unsigned)y0 < 64u, vy1 = (unsigned)y1 < 64u;
    bool vx0 = (unsigned)x0 < 64u, vx1 = (unsigned)x1 < 64u;
    int cy0 = min(max(y0, 0), 63), cy1 = min(max(y1, 0), 63);
    int cx0 = min(max(x0, 0), 63), cx1 = min(max(x1, 0), 63);
    mwt.x = (vy0 && vx0) ? hy * hx * m : 0.f;
    mwt.y = (vy0 && vx1) ? hy * lx * m : 0.f;
    mwt.z = (vy1 && vx0) ? ly * hx * m : 0.f;
    mwt.w = (vy1 && vx1) ? ly * lx * m : 0.f;
    mi = make_int4(cy0 * 64 + cx0, cy0 * 64 + cx1, cy1 * 64 + cx0, cy1 * 64 + cx1);
  };

  auto fetch = [&](int c) {
    if ((c & 7) == 0) compute_md(c >> 3);
    int cb = (c & 7) * 4 + cg;          // f16x8 octet within pixel
    v0 = gin[mi.x * 32 + cb];
    v1 = gin[mi.y * 32 + cb];
    v2 = gin[mi.z * 32 + cb];
    v3 = gin[mi.w * 32 + cb];
#pragma unroll
    for (int q = 0; q < 4; ++q)
      wv[q] = wg4[c * 1024 + q * 256 + tid];
  };

  auto stage = [&](int nb) {
    f16x8 s = v0 * sp8((_Float16)mwt.x) + v1 * sp8((_Float16)mwt.y)
            + v2 * sp8((_Float16)mwt.z) + v3 * sp8((_Float16)mwt.w);
    *(f16x8*)(&Sl[nb][pos * SROW + cg * 8]) = s;
#pragma unroll
    for (int q = 0; q < 4; ++q)
      ((uint4*)&Wl[nb][0])[q * 256 + tid] = wv[q];
  };

  f32x4 acc[4][4];
#pragma unroll
  for (int mt = 0; mt < 4; ++mt)
#pragma unroll
    for (int nt = 0; nt < 4; ++nt) {
      acc[mt][nt][0] = 0.f; acc[mt][nt][1] = 0.f;
      acc[mt][nt][2] = 0.f; acc[mt][nt][3] = 0.f;
    }

  // prologue
  fetch(0);
  stage(0);
  __syncthreads();

  for (int c = 0; c < NCHUNK; ++c) {
    const int cur = c & 1;
    if (c + 1 < NCHUNK) fetch(c + 1);   // loads in flight during MFMA

    const _Float16* WlB = &Wl[cur][lq * 2048 + (wm * 64 + lr) * 8];
    const _Float16* SlB = &Sl[cur][lr * SROW + lq * 8];
    f16x8 afr[4];
#pragma unroll
    for (int mt = 0; mt < 4; ++mt) afr[mt] = *(const f16x8*)(WlB + mt * 128);
#pragma unroll
    for (int nt = 0; nt < 4; ++nt) {
      f16x8 bfr = *(const f16x8*)(SlB + nt * 16 * SROW);
#pragma unroll
      for (int mt = 0; mt < 4; ++mt)
        acc[mt][nt] = __builtin_amdgcn_mfma_f32_16x16x32_f16(afr[mt], bfr, acc[mt][nt], 0, 0, 0);
    }
    if (c + 1 < NCHUNK) stage(cur ^ 1);
    __syncthreads();
  }

  // ---- epilogue: bias + store ----
#pragma unroll
  for (int mt = 0; mt < 4; ++mt) {
#pragma unroll
    for (int reg = 0; reg < 4; ++reg) {
      int o = wm * 64 + mt * 16 + lq * 4 + reg;
      float bv = bias[o];
      float* op = out + ((size_t)(b * 256 + o)) * 4096 + rp * 64 + lr;
#pragma unroll
      for (int nt = 0; nt < 4; ++nt)
        op[nt * 16] = acc[mt][nt][reg] + bv;
    }
  }
}

extern "C" void kernel_launch(void* const* d_in, const int* in_sizes, int n_in,
                              void* d_out, int out_size, void* d_ws, size_t ws_size,
                              hipStream_t stream) {
  const float* inp    = (const float*)d_in[0];
  const float* offset = (const float*)d_in[1];
  const float* mask   = (const float*)d_in[2];
  const float* weight = (const float*)d_in[3];
  const float* bias   = (const float*)d_in[4];
  float* out = (float*)d_out;

  _Float16* inh = (_Float16*)d_ws;                       // 16.78 MB
  _Float16* wgh = inh + (size_t)Bb * HW * Cc;            // +1.18 MB

  hipLaunchKernelGGL(nchw_to_nhwc_f16, dim3(128, Bb), dim3(256), 0, stream, inp, inh);
  hipLaunchKernelGGL(wcvt, dim3(288), dim3(256), 0, stream, weight, wgh);
  // grid x = batch -> linear%8 = XCD-affine; y = output row
  hipLaunchKernelGGL(dcn_mfma, dim3(Bb, 64), dim3(256), 0, stream,
                     inh, wgh, offset, mask, bias, out);
}

// Round 6
// 173.654 us; speedup vs baseline: 1.9019x; 1.6444x over previous
//
#include <hip/hip_runtime.h>

typedef _Float16 f16x8 __attribute__((ext_vector_type(8)));
typedef float    f32x4 __attribute__((ext_vector_type(4)));

namespace {
constexpr int Bb = 8, Cc = 256, Oo = 256;
constexpr int HW = 4096;                 // 64x64
constexpr int NCHUNK = 72;               // 2304 / 32
constexpr int SROW = 40;                 // Sl row stride (f16), pad 32->40
}

__device__ inline f16x8 sp8(_Float16 x) { f16x8 r = {x,x,x,x,x,x,x,x}; return r; }

// ---------- pre-kernel 1: NCHW fp32 -> NHWC fp16 ----------
__global__ __launch_bounds__(256)
void nchw_to_nhwc_f16(const float* __restrict__ in, _Float16* __restrict__ outh) {
  const int tid = threadIdx.x;
  const int b   = blockIdx.y;
  const int px  = blockIdx.x * 32 + (tid >> 3);
  const int c8s = tid & 7;
  const float* src = in + (size_t)b * Cc * HW + px;
  _Float16*    dst = outh + ((size_t)b * HW + px) * Cc;
#pragma unroll
  for (int q = 0; q < 4; ++q) {
    int c8 = q * 8 + c8s;
    f16x8 v;
#pragma unroll
    for (int j = 0; j < 8; ++j)
      v[j] = (_Float16)src[(size_t)(c8 * 8 + j) * HW];
    *(f16x8*)(dst + c8 * 8) = v;
  }
}

// ---------- pre-kernel 2: weight fp32 [O][C][9] -> fp16 [chunk][kq][o][k8] ----------
__global__ __launch_bounds__(256)
void wcvt(const float* __restrict__ w, _Float16* __restrict__ wh) {
  int t   = blockIdx.x * 256 + threadIdx.x;   // 0..73727
  int o   = t & 255;
  int Kb  = (t >> 8) * 8;
  const float* s = w + (size_t)o * 2304;
  f16x8 v;
#pragma unroll
  for (int k8 = 0; k8 < 8; ++k8) {
    int K = Kb + k8;
    int tap = K >> 8, c = K & 255;
    v[k8] = (_Float16)s[c * 9 + tap];
  }
  *(f16x8*)(wh + (size_t)t * 8) = v;
}

// ---------- main kernel: R3 structure (256 blocks x 512 thr, 256o x 128p) ----------
// + XCD-affine grid, + weights direct global->register A-fragments (no Wl LDS),
// + offset/mask inputs prefetched one chunk ahead of md rebuild.
__global__ __launch_bounds__(512, 2)
void dcn_mfma(const _Float16* __restrict__ inh,   // [B][4096][256] fp16 NHWC
              const _Float16* __restrict__ wgh,   // [72][4][256][8] fp16 (A-frag order)
              const float* __restrict__ offset,
              const float* __restrict__ mask,
              const float* __restrict__ bias,
              float* __restrict__ out) {
  __shared__ __align__(16) _Float16 Sl[2][128 * SROW];  // 20 KB total

  const int tid = threadIdx.x;
  const int b   = blockIdx.x;   // 0..7  -> linear%8 -> XCD-affine batch
  const int rp  = blockIdx.y;   // 0..31 -> rows 2rp, 2rp+1

  // sampling role: pos in [0,128), cg in [0,4); 4 lanes = 64 B contiguous per pixel
  const int pos = tid >> 2, cg = tid & 3;
  const int ho  = rp * 2 + (pos >> 6), wo = pos & 63;
  // MFMA role: 8 waves, wave tile 64(o) x 64(p)
  const int lane = tid & 63, wid = tid >> 6;
  const int wm = wid >> 1, wn = wid & 1;
  const int lq = lane >> 4, lr = lane & 15;

  const f16x8* gin = (const f16x8*)(inh + (size_t)b * HW * Cc);
  const uint4* wg4 = (const uint4*)wgh;
  const int    wbase = lq * 256 + wm * 64 + lr;   // uint4 index within chunk

  int4   mi;   float4 mwt;
  float  ofy, ofx, msk;          // md inputs (prefetched)
  f16x8  v0, v1, v2, v3;         // gathered corners (chunk in flight)
  uint4  awv[4];                 // A-fragments   (chunk in flight)

  auto load_md_inputs = [&](int tap) {
    ofy = offset[(((size_t)b * 18 + 2 * tap)     * 64 + ho) * 64 + wo];
    ofx = offset[(((size_t)b * 18 + 2 * tap + 1) * 64 + ho) * 64 + wo];
    msk = mask  [(((size_t)b * 9  + tap)         * 64 + ho) * 64 + wo];
  };
  auto build_md = [&](int tap) {
    int ki = tap / 3, kj = tap % 3;
    float y = ofy + (float)(ho - 1 + ki);
    float x = ofx + (float)(wo - 1 + kj);
    float y0f = floorf(y), x0f = floorf(x);
    float ly = y - y0f, lx = x - x0f;
    float hy = 1.f - ly, hx = 1.f - lx;
    int y0 = (int)y0f, x0 = (int)x0f;
    int y1 = y0 + 1, x1 = x0 + 1;
    bool vy0 = (unsigned)y0 < 64u, vy1 = (unsigned)y1 < 64u;
    bool vx0 = (unsigned)x0 < 64u, vx1 = (unsigned)x1 < 64u;
    int cy0 = min(max(y0, 0), 63), cy1 = min(max(y1, 0), 63);
    int cx0 = min(max(x0, 0), 63), cx1 = min(max(x1, 0), 63);
    mwt.x = (vy0 && vx0) ? hy * hx * msk : 0.f;
    mwt.y = (vy0 && vx1) ? hy * lx * msk : 0.f;
    mwt.z = (vy1 && vx0) ? ly * hx * msk : 0.f;
    mwt.w = (vy1 && vx1) ? ly * lx * msk : 0.f;
    mi = make_int4(cy0 * 64 + cx0, cy0 * 64 + cx1, cy1 * 64 + cx0, cy1 * 64 + cx1);
  };
  auto gather = [&](int c) {
    if ((c & 7) == 0) build_md(c >> 3);              // pure VALU (inputs prefetched)
    int cb = (c & 7) * 4 + cg;
    v0 = gin[mi.x * 32 + cb];
    v1 = gin[mi.y * 32 + cb];
    v2 = gin[mi.z * 32 + cb];
    v3 = gin[mi.w * 32 + cb];
    if ((c & 7) == 7) load_md_inputs((c >> 3) + 1);  // one chunk ahead of rebuild
  };
  auto stage = [&](int nb) {
    f16x8 s = v0 * sp8((_Float16)mwt.x) + v1 * sp8((_Float16)mwt.y)
            + v2 * sp8((_Float16)mwt.z) + v3 * sp8((_Float16)mwt.w);
    *(f16x8*)(&Sl[nb][pos * SROW + cg * 8]) = s;
  };
  auto wload = [&](int c) {
    const uint4* base = wg4 + (size_t)c * 1024 + wbase;
#pragma unroll
    for (int mt = 0; mt < 4; ++mt) awv[mt] = base[mt * 16];
  };

  f32x4 acc[4][4];
#pragma unroll
  for (int mt = 0; mt < 4; ++mt)
#pragma unroll
    for (int nt = 0; nt < 4; ++nt) {
      acc[mt][nt][0] = 0.f; acc[mt][nt][1] = 0.f;
      acc[mt][nt][2] = 0.f; acc[mt][nt][3] = 0.f;
    }

  // prologue: md inputs + md + chunk0 gather/weights, stage buf0
  load_md_inputs(0);
  gather(0);            // builds md(0) after inputs land, issues gathers
  wload(0);
  stage(0);
  __syncthreads();

  for (int c = 0; c < NCHUNK; ++c) {
    const int cur = c & 1;
    if (c + 1 < NCHUNK) gather(c + 1);     // gathers in flight during MFMA

    // A-fragments for THIS chunk from registers (loaded last iteration)
    f16x8 afr[4];
#pragma unroll
    for (int mt = 0; mt < 4; ++mt) afr[mt] = __builtin_bit_cast(f16x8, awv[mt]);

    const _Float16* SlB = &Sl[cur][(wn * 64 + lr) * SROW + lq * 8];
#pragma unroll
    for (int nt = 0; nt < 4; ++nt) {
      f16x8 bfr = *(const f16x8*)(SlB + nt * 16 * SROW);
#pragma unroll
      for (int mt = 0; mt < 4; ++mt)
        acc[mt][nt] = __builtin_amdgcn_mfma_f32_16x16x32_f16(afr[mt], bfr, acc[mt][nt], 0, 0, 0);
    }

    if (c + 1 < NCHUNK) {
      wload(c + 1);                        // overwrite awv after afr copy
      stage(cur ^ 1);                      // consume gathers, write next S buf
    }
    __syncthreads();
  }

  // ---- epilogue: bias + store (R3 pattern) ----
  const int pbase = rp * 128 + wn * 64 + lr;
#pragma unroll
  for (int mt = 0; mt < 4; ++mt) {
#pragma unroll
    for (int reg = 0; reg < 4; ++reg) {
      int o = wm * 64 + mt * 16 + lq * 4 + reg;
      float bv = bias[o];
      float* op = out + ((size_t)(b * 256 + o)) * 4096 + pbase;
#pragma unroll
      for (int nt = 0; nt < 4; ++nt)
        op[nt * 16] = acc[mt][nt][reg] + bv;
    }
  }
}

extern "C" void kernel_launch(void* const* d_in, const int* in_sizes, int n_in,
                              void* d_out, int out_size, void* d_ws, size_t ws_size,
                              hipStream_t stream) {
  const float* inp    = (const float*)d_in[0];
  const float* offset = (const float*)d_in[1];
  const float* mask   = (const float*)d_in[2];
  const float* weight = (const float*)d_in[3];
  const float* bias   = (const float*)d_in[4];
  float* out = (float*)d_out;

  _Float16* inh = (_Float16*)d_ws;                       // 16.78 MB
  _Float16* wgh = inh + (size_t)Bb * HW * Cc;            // +1.18 MB

  hipLaunchKernelGGL(nchw_to_nhwc_f16, dim3(128, Bb), dim3(256), 0, stream, inp, inh);
  hipLaunchKernelGGL(wcvt, dim3(288), dim3(256), 0, stream, weight, wgh);
  // grid: x=b -> linear%8 = batch -> XCD-affine; y = row pair
  hipLaunchKernelGGL(dcn_mfma, dim3(Bb, 32), dim3(512), 0, stream,
                     inh, wgh, offset, mask, bias, out);
}